// Round 2
// baseline (2882.677 us; speedup 1.0000x reference)
//
#include <hip/hip_runtime.h>
#include <hip/hip_bf16.h>
#include <math.h>

// ---- problem constants ----
#define B_SZ     2
#define SEQ      4096
#define DMODEL   1024
#define DSTATE   128
#define HEADDIM  64
#define CHUNK    256
#define DINNER   2048
#define DSSM     2048
#define NHEADS   32
#define CONVDIM  2304       // DSSM + 2*DSTATE
#define DOUTSZ   1024
#define NC       16         // SEQ / CHUNK
#define EPSF     1e-5f

typedef __hip_bfloat16 bf16;

__device__ __forceinline__ float siluf(float x) { return x / (1.0f + expf(-x)); }

__device__ __forceinline__ float bfu(unsigned short u) {
    union { unsigned int i; float f; } c; c.i = ((unsigned int)u) << 16; return c.f;
}
__device__ __forceinline__ float ldf(const float* p) { return *p; }
__device__ __forceinline__ float ldf(const bf16* p) { return __bfloat162float(*p); }

// 4-element contiguous load -> fp32
__device__ __forceinline__ void ld4(const float* p, float* d) {
    float4 v = *(const float4*)p; d[0] = v.x; d[1] = v.y; d[2] = v.z; d[3] = v.w;
}
__device__ __forceinline__ void ld4(const bf16* p, float* d) {
    ushort4 v = *(const ushort4*)(const void*)p;
    d[0] = bfu(v.x); d[1] = bfu(v.y); d[2] = bfu(v.z); d[3] = bfu(v.w);
}
__device__ __forceinline__ void stc(float* p, float v) { *p = v; }
__device__ __forceinline__ void stc(bf16* p, float v) { *p = __float2bfloat16(v); }

// ============================================================
// Generic NT GEMM: C[m,n] = sum_k A[m*lda+k] * B[n*ldb+k]
// 64x64 tile, BK=16, 256 threads, 4x4 micro-tile. Batched via blockIdx.z.
// B operand is always fp32. A/C types templated.
// ============================================================
#define BM 64
#define BN 64
#define BKK 16

template<typename TA, typename TC>
__global__ __launch_bounds__(256)
void gemm_nt(const TA* __restrict__ A, const float* __restrict__ B,
             TC* __restrict__ C, int M, int N, int K,
             int lda, int ldb, int ldc,
             long long sA, long long sB, long long sC)
{
    A += (long long)blockIdx.z * sA;
    B += (long long)blockIdx.z * sB;
    C += (long long)blockIdx.z * sC;

    __shared__ float As[BM][BKK + 1];
    __shared__ float Bs[BN][BKK + 1];

    const int tid = threadIdx.x;
    const int tx = tid & 15;        // n direction
    const int ty = tid >> 4;        // m direction
    const int m0 = blockIdx.y * BM;
    const int n0 = blockIdx.x * BN;

    const int lrow = tid >> 2;          // 0..63
    const int lk4  = (tid & 3) * 4;     // 0,4,8,12

    float acc[4][4] = {};

    for (int k0 = 0; k0 < K; k0 += BKK) {
        {
            int gm = m0 + lrow;
            float v[4] = {0.f, 0.f, 0.f, 0.f};
            if (gm < M) ld4(A + (long long)gm * lda + k0 + lk4, v);
            As[lrow][lk4 + 0] = v[0]; As[lrow][lk4 + 1] = v[1];
            As[lrow][lk4 + 2] = v[2]; As[lrow][lk4 + 3] = v[3];
        }
        {
            int gn = n0 + lrow;
            float v[4] = {0.f, 0.f, 0.f, 0.f};
            if (gn < N) ld4(B + (long long)gn * ldb + k0 + lk4, v);
            Bs[lrow][lk4 + 0] = v[0]; Bs[lrow][lk4 + 1] = v[1];
            Bs[lrow][lk4 + 2] = v[2]; Bs[lrow][lk4 + 3] = v[3];
        }
        __syncthreads();
        #pragma unroll
        for (int kk = 0; kk < BKK; ++kk) {
            float a[4], b[4];
            #pragma unroll
            for (int i = 0; i < 4; ++i) a[i] = As[ty * 4 + i][kk];
            #pragma unroll
            for (int j = 0; j < 4; ++j) b[j] = Bs[tx * 4 + j][kk];
            #pragma unroll
            for (int i = 0; i < 4; ++i)
                #pragma unroll
                for (int j = 0; j < 4; ++j)
                    acc[i][j] += a[i] * b[j];
        }
        __syncthreads();
    }
    #pragma unroll
    for (int i = 0; i < 4; ++i) {
        int gm = m0 + ty * 4 + i;
        if (gm >= M) continue;
        #pragma unroll
        for (int j = 0; j < 4; ++j) {
            int gn = n0 + tx * 4 + j;
            if (gn < N) stc(&C[(long long)gm * ldc + gn], acc[i][j]);
        }
    }
}

// ============================================================
// Depthwise causal conv (width 4) + bias + SiLU over xBC, split outputs.
// grid: B*SEQ*9 blocks of 256 (CONVDIM = 9*256)
// ============================================================
__global__ __launch_bounds__(256)
void conv_silu(const bf16* __restrict__ xbc, const float* __restrict__ cw,
               const float* __restrict__ cb,
               bf16* __restrict__ xconv, float* __restrict__ Bc,
               float* __restrict__ Cc)
{
    const int tid = threadIdx.x;
    const int c  = (blockIdx.x % 9) * 256 + tid;     // [0, 2304)
    const int lf = blockIdx.x / 9;                   // b*SEQ + l
    const int b  = lf / SEQ;
    const int l  = lf % SEQ;

    float acc = cb[c];
    #pragma unroll
    for (int k = 0; k < 4; ++k) {
        int ls = l - 3 + k;
        if (ls >= 0)
            acc += __bfloat162float(xbc[((long long)(b * SEQ + ls)) * CONVDIM + c]) * cw[c * 4 + k];
    }
    float v = siluf(acc);
    if (c < DSSM)
        xconv[(long long)lf * DSSM + c] = __float2bfloat16(v);
    else if (c < DSSM + DSTATE)
        Bc[(long long)lf * DSTATE + (c - DSSM)] = v;
    else
        Cc[(long long)lf * DSTATE + (c - DSSM - DSTATE)] = v;
}

// ============================================================
// dtp = softplus(dt_raw + dt_bias). grid: B*SEQ*NHEADS/256 = 1024 blocks
// ============================================================
__global__ __launch_bounds__(256)
void dtproj(const float* __restrict__ dtraw, const float* __restrict__ dt_bias,
            float* __restrict__ dtp)
{
    int f = blockIdx.x * 256 + threadIdx.x;   // (b*SEQ+l)*32 + h
    int h = f & 31;
    float x = dtraw[f] + dt_bias[h];
    dtp[f] = (x > 20.f) ? x : log1pf(expf(x));
}

// ============================================================
// Per-(b,h,chunk) inclusive cumsum of dA = dtp * A.
// ============================================================
__global__ __launch_bounds__(256)
void cumsum_da(const float* __restrict__ dtp, const float* __restrict__ A_log,
               float* __restrict__ cs)
{
    const int bid = blockIdx.x;
    const int z = bid % NC;
    const int h = (bid / NC) % NHEADS;
    const int b = bid / (NC * NHEADS);
    const int t = threadIdx.x;

    const float Ah = -expf(A_log[h]);
    const int lg = z * CHUNK + t;
    float v = dtp[((long long)(b * SEQ) + lg) * NHEADS + h] * Ah;

    __shared__ float s[CHUNK];
    s[t] = v;
    __syncthreads();
    for (int off = 1; off < CHUNK; off <<= 1) {
        float add = (t >= off) ? s[t - off] : 0.f;
        __syncthreads();
        s[t] += add;
        __syncthreads();
    }
    cs[((long long)(b * NHEADS) + h) * SEQ + lg] = s[t];
}

// ============================================================
// Y_diag: per (b,z,h) block. y[l,p] = sum_{s<=l} S[l,s]*exp(cs_l-cs_s)*xd[s,p]
// ============================================================
__global__ __launch_bounds__(256)
void ydiag(const bf16* __restrict__ S, const bf16* __restrict__ xconv,
           const float* __restrict__ dtp, const float* __restrict__ cs,
           bf16* __restrict__ y)
{
    const int h  = blockIdx.x % NHEADS;
    const int bz = blockIdx.x / NHEADS;
    const int z  = bz % NC;
    const int b  = bz / NC;
    const int l  = threadIdx.x;

    __shared__ float Ss[CHUNK][17];
    __shared__ float xds[16][HEADDIM];
    __shared__ float css[CHUNK];

    const bf16* Sb = S + (long long)bz * CHUNK * CHUNK;
    const long long rowbase = (long long)b * SEQ + (long long)z * CHUNK;

    css[l] = cs[((long long)(b * NHEADS) + h) * SEQ + z * CHUNK + l];

    float acc[HEADDIM];
    #pragma unroll
    for (int p = 0; p < HEADDIM; ++p) acc[p] = 0.f;
    __syncthreads();
    const float cl = css[l];

    for (int s0 = 0; s0 < CHUNK; s0 += 16) {
        #pragma unroll
        for (int j = 0; j < 16; ++j) {
            int flat = j * 256 + threadIdx.x;
            int row = flat >> 4, sc = flat & 15;
            Ss[row][sc] = __bfloat162float(Sb[row * CHUNK + s0 + sc]);
        }
        {
            int p  = threadIdx.x & 63;
            int sl = threadIdx.x >> 6;   // 0..3
            #pragma unroll
            for (int j = 0; j < 4; ++j) {
                int s = s0 + sl + j * 4;
                long long lg = rowbase + s;
                xds[sl + j * 4][p] =
                    __bfloat162float(xconv[lg * DSSM + h * 64 + p]) * dtp[lg * NHEADS + h];
            }
        }
        __syncthreads();
        int smax = l - s0 + 1;
        if (smax > 16) smax = 16;
        for (int sl = 0; sl < smax; ++sl) {
            float w = Ss[l][sl] * expf(cl - css[s0 + sl]);
            #pragma unroll
            for (int p = 0; p < HEADDIM; p += 4) {
                float4 xv = *(const float4*)&xds[sl][p];
                acc[p + 0] += w * xv.x; acc[p + 1] += w * xv.y;
                acc[p + 2] += w * xv.z; acc[p + 3] += w * xv.w;
            }
        }
        __syncthreads();
    }
    bf16* outr = y + (rowbase + l) * DSSM + h * 64;
    #pragma unroll
    for (int p = 0; p < HEADDIM; ++p)
        outr[p] = __float2bfloat16(acc[p]);
}

// ============================================================
// states[p,n] = sum_l Bm[l,n]*exp(cs_last-cs_l)*xd[l,p]  per (b,z,h)
// ============================================================
__global__ __launch_bounds__(256)
void chunk_states(const float* __restrict__ Bcp, const bf16* __restrict__ xconv,
                  const float* __restrict__ dtp, const float* __restrict__ cs,
                  float* __restrict__ states)
{
    const int h  = blockIdx.x % NHEADS;
    const int bz = blockIdx.x / NHEADS;
    const int z  = bz % NC;
    const int b  = bz / NC;
    const int tid = threadIdx.x;

    __shared__ float Bd[16][DSTATE];
    __shared__ float xdt[16][HEADDIM];
    __shared__ float css[CHUNK];
    __shared__ float dec[CHUNK];

    css[tid] = cs[((long long)(b * NHEADS) + h) * SEQ + z * CHUNK + tid];
    __syncthreads();
    const float cslast = css[CHUNK - 1];
    dec[tid] = expf(cslast - css[tid]);
    __syncthreads();

    const int tx = tid & 31;   // n0 = tx*4
    const int ty = tid >> 5;   // p0 = ty*8
    const long long rowbase = (long long)b * SEQ + (long long)z * CHUNK;

    float acc[8][4] = {};

    for (int l0 = 0; l0 < CHUNK; l0 += 16) {
        #pragma unroll
        for (int j = 0; j < 8; ++j) {
            int flat = j * 256 + tid;
            int ll = flat >> 7, n = flat & 127;
            int lg = l0 + ll;
            Bd[ll][n] = Bcp[(rowbase + lg) * DSTATE + n] * dec[lg];
        }
        #pragma unroll
        for (int j = 0; j < 4; ++j) {
            int flat = j * 256 + tid;
            int ll = flat >> 6, p = flat & 63;
            int lg = l0 + ll;
            xdt[ll][p] = __bfloat162float(xconv[(rowbase + lg) * DSSM + h * 64 + p])
                       * dtp[(rowbase + lg) * NHEADS + h];
        }
        __syncthreads();
        #pragma unroll
        for (int ll = 0; ll < 16; ++ll) {
            float bv[4];
            #pragma unroll
            for (int j = 0; j < 4; ++j) bv[j] = Bd[ll][tx * 4 + j];
            #pragma unroll
            for (int i = 0; i < 8; ++i) {
                float a = xdt[ll][ty * 8 + i];
                #pragma unroll
                for (int j = 0; j < 4; ++j) acc[i][j] += a * bv[j];
            }
        }
        __syncthreads();
    }
    float* st = states + ((long long)(bz * NHEADS + h)) * HEADDIM * DSTATE;
    #pragma unroll
    for (int i = 0; i < 8; ++i) {
        int p = ty * 8 + i;
        float4 v = make_float4(acc[i][0], acc[i][1], acc[i][2], acc[i][3]);
        *(float4*)(st + p * DSTATE + tx * 4) = v;
    }
}

// ============================================================
// Inter-chunk scan (in place: states[z] <- prev[z]).
// ============================================================
__global__ __launch_bounds__(256)
void chunk_scan(float* __restrict__ states, const float* __restrict__ cs)
{
    int f = blockIdx.x * 256 + threadIdx.x;
    int n = f & 127;
    int p = (f >> 7) & 63;
    int h = (f >> 13) & 31;
    int b = f >> 18;

    float carry = 0.f;
    for (int z = 0; z < NC; ++z) {
        long long idx = ((((long long)(b * NC + z) * NHEADS) + h) * HEADDIM + p) * DSTATE + n;
        float st = states[idx];
        states[idx] = carry;
        float cd = expf(cs[((long long)(b * NHEADS) + h) * SEQ + z * CHUNK + CHUNK - 1]);
        carry = carry * cd + st;
    }
}

// ============================================================
// Y_off + combine: y[l,p] += exp(cs_l)*sum_n C[l,n]*prev[p,n] + D_h*x4[l,p]
// ============================================================
__global__ __launch_bounds__(256)
void yoff_combine(const float* __restrict__ Cc, const float* __restrict__ prev,
                  const bf16* __restrict__ xconv, const float* __restrict__ cs,
                  const float* __restrict__ Dv, bf16* __restrict__ y)
{
    const int h  = blockIdx.x % NHEADS;
    const int bz = blockIdx.x / NHEADS;
    const int z  = bz % NC;
    const int b  = bz / NC;
    const int tid = threadIdx.x;
    const int l = tid;

    __shared__ float prevS[HEADDIM][DSTATE];   // 32 KB
    __shared__ float Cst[CHUNK][17];
    __shared__ float css[CHUNK];

    const float* pv = prev + (long long)(bz * NHEADS + h) * HEADDIM * DSTATE;
    #pragma unroll
    for (int j = 0; j < 32; ++j) {
        int flat = j * 256 + tid;
        prevS[flat >> 7][flat & 127] = pv[flat];
    }
    css[tid] = cs[((long long)(b * NHEADS) + h) * SEQ + z * CHUNK + tid];
    __syncthreads();

    const long long rowbase = (long long)b * SEQ + (long long)z * CHUNK;
    float acc[HEADDIM];
    #pragma unroll
    for (int p = 0; p < HEADDIM; ++p) acc[p] = 0.f;

    for (int n0 = 0; n0 < DSTATE; n0 += 16) {
        #pragma unroll
        for (int j = 0; j < 16; ++j) {
            int flat = j * 256 + tid;
            int row = flat >> 4, nc2 = flat & 15;
            Cst[row][nc2] = Cc[(rowbase + row) * DSTATE + n0 + nc2];
        }
        __syncthreads();
        float cv[16];
        #pragma unroll
        for (int nl = 0; nl < 16; ++nl) cv[nl] = Cst[l][nl];
        #pragma unroll
        for (int p = 0; p < HEADDIM; ++p) {
            #pragma unroll
            for (int q = 0; q < 16; q += 4) {
                float4 pr = *(const float4*)&prevS[p][n0 + q];
                acc[p] += cv[q + 0] * pr.x + cv[q + 1] * pr.y
                        + cv[q + 2] * pr.z + cv[q + 3] * pr.w;
            }
        }
        __syncthreads();
    }
    const float el = expf(css[l]);
    const float Dh = Dv[h];
    bf16* yr = y + (rowbase + l) * DSSM + h * 64;
    const bf16* xr = xconv + (rowbase + l) * DSSM + h * 64;
    #pragma unroll
    for (int p = 0; p < HEADDIM; ++p) {
        float yd = __bfloat162float(yr[p]);
        float xv = __bfloat162float(xr[p]);
        yr[p] = __float2bfloat16(yd + el * acc[p] + Dh * xv);
    }
}

// ============================================================
// Gated RMSNorm: t = y*silu(z); y = t*rsqrt(mean(t^2)+eps)*norm_w  (in place)
// ============================================================
__global__ __launch_bounds__(256)
void gated_rmsnorm(bf16* __restrict__ y, const bf16* __restrict__ z,
                   const float* __restrict__ nw)
{
    const int row = blockIdx.x;
    const int tid = threadIdx.x;
    bf16* yr = y + (long long)row * DSSM;
    const bf16* zr = z + (long long)row * DSSM;

    float t[8];
    float ss = 0.f;
    const int c0 = tid * 8;
    #pragma unroll
    for (int j = 0; j < 8; ++j) {
        float zv = __bfloat162float(zr[c0 + j]);
        float tv = __bfloat162float(yr[c0 + j]) * siluf(zv);
        t[j] = tv;
        ss += tv * tv;
    }
    #pragma unroll
    for (int off = 32; off > 0; off >>= 1) ss += __shfl_down(ss, off);
    __shared__ float red[4];
    if ((tid & 63) == 0) red[tid >> 6] = ss;
    __syncthreads();
    float tot = red[0] + red[1] + red[2] + red[3];
    float rs = rsqrtf(tot / (float)DSSM + EPSF);
    #pragma unroll
    for (int j = 0; j < 8; ++j)
        yr[c0 + j] = __float2bfloat16(t[j] * rs * nw[c0 + j]);
}

// ============================================================
extern "C" void kernel_launch(void* const* d_in, const int* in_sizes, int n_in,
                              void* d_out, int out_size, void* d_ws, size_t ws_size,
                              hipStream_t stream)
{
    const float* inp     = (const float*)d_in[0];
    const float* W_in    = (const float*)d_in[1];
    const float* conv_w  = (const float*)d_in[2];
    const float* conv_b  = (const float*)d_in[3];
    const float* dt_bias = (const float*)d_in[4];
    const float* A_log   = (const float*)d_in[5];
    const float* Dv      = (const float*)d_in[6];
    const float* norm_w  = (const float*)d_in[7];
    const float* W_out   = (const float*)d_in[8];
    float* out = (float*)d_out;

    char* ws = (char*)d_ws;
    size_t off = 0;
    auto alloc = [&](size_t bytes) -> void* {
        void* p = (void*)(ws + off);
        off = (off + bytes + 255) & ~(size_t)255;
        return p;
    };
    const int MR = B_SZ * SEQ;   // 8192 token rows

    bf16*  zb     = (bf16*) alloc((size_t)MR * DSSM * 2);            // 33.5 MB (lives to rmsnorm)
    bf16*  xbc    = (bf16*) alloc((size_t)MR * CONVDIM * 2);         // 37.75 MB (dead after conv)
    bf16*  xconv  = (bf16*) alloc((size_t)MR * DSSM * 2);            // 33.5 MB
    float* Bc     = (float*)alloc((size_t)MR * DSTATE * 4);          // 4.2 MB
    float* Cc     = (float*)alloc((size_t)MR * DSTATE * 4);          // 4.2 MB
    float* dtraw  = (float*)alloc((size_t)MR * NHEADS * 4);          // 1 MB
    float* dtp    = (float*)alloc((size_t)MR * NHEADS * 4);          // 1 MB
    float* cs     = (float*)alloc((size_t)B_SZ * NHEADS * SEQ * 4);  // 1 MB
    float* states = (float*)alloc((size_t)B_SZ * NC * NHEADS * HEADDIM * DSTATE * 4); // 33.5 MB
    // alias Smat + ybuf into the dead xbc region (4.19 MB + 33.55 MB == 37.75 MB exactly)
    bf16*  Smat   = (bf16*)xbc;
    bf16*  ybuf   = (bf16*)((char*)xbc + (size_t)B_SZ * NC * CHUNK * CHUNK * 2);
    // total ws: ~150 MB

    dim3 blk(256);

    // 1) in_proj GEMM, split into z | xBC | dt_raw
    gemm_nt<float, bf16><<<dim3(DSSM / BN, MR / BM, 1), blk, 0, stream>>>(
        inp, W_in, zb, MR, DSSM, DMODEL, DMODEL, DMODEL, DSSM, 0, 0, 0);
    gemm_nt<float, bf16><<<dim3(CONVDIM / BN, MR / BM, 1), blk, 0, stream>>>(
        inp, W_in + (size_t)DSSM * DMODEL, xbc, MR, CONVDIM, DMODEL, DMODEL, DMODEL, CONVDIM, 0, 0, 0);
    gemm_nt<float, float><<<dim3(1, MR / BM, 1), blk, 0, stream>>>(
        inp, W_in + (size_t)(DSSM + CONVDIM) * DMODEL, dtraw, MR, NHEADS, DMODEL, DMODEL, DMODEL, NHEADS, 0, 0, 0);

    // 2) conv + silu + split  (reads xbc; xbc dead afterwards)
    conv_silu<<<dim3(MR * 9), blk, 0, stream>>>(xbc, conv_w, conv_b, xconv, Bc, Cc);

    // 3) dtp = softplus(dt_raw + dt_bias)
    dtproj<<<dim3(MR * NHEADS / 256), blk, 0, stream>>>(dtraw, dt_bias, dtp);

    // 4) cumsum of dA per (b,h,chunk)
    cumsum_da<<<dim3(B_SZ * NHEADS * NC), blk, 0, stream>>>(dtp, A_log, cs);

    // 5) S = Cm @ Bm^T per (b,chunk)  [batched GEMM] -> bf16 Smat (aliases xbc)
    gemm_nt<float, bf16><<<dim3(CHUNK / BN, CHUNK / BM, B_SZ * NC), blk, 0, stream>>>(
        Cc, Bc, Smat, CHUNK, CHUNK, DSTATE, DSTATE, DSTATE, CHUNK,
        (long long)CHUNK * DSTATE, (long long)CHUNK * DSTATE, (long long)CHUNK * CHUNK);

    // 6) Y_diag -> ybuf (aliases xbc tail)
    ydiag<<<dim3(B_SZ * NC * NHEADS), blk, 0, stream>>>(Smat, xconv, dtp, cs, ybuf);

    // 7) per-chunk states
    chunk_states<<<dim3(B_SZ * NC * NHEADS), blk, 0, stream>>>(Bc, xconv, dtp, cs, states);

    // 8) inter-chunk scan (in place -> prev)
    chunk_scan<<<dim3(B_SZ * NHEADS * HEADDIM * DSTATE / 256), blk, 0, stream>>>(states, cs);

    // 9) Y_off + D*x combine
    yoff_combine<<<dim3(B_SZ * NC * NHEADS), blk, 0, stream>>>(Cc, states, xconv, cs, Dv, ybuf);

    // 10) gated RMSNorm (in place on ybuf)
    gated_rmsnorm<<<dim3(MR), blk, 0, stream>>>(ybuf, zb, norm_w);

    // 11) out GEMM: out = ybuf @ W_out^T
    gemm_nt<bf16, float><<<dim3(DOUTSZ / BN, MR / BM, 1), blk, 0, stream>>>(
        ybuf, W_out, out, MR, DOUTSZ, DINNER, DINNER, DINNER, DOUTSZ, 0, 0, 0);
}

// Round 3
// 1095.802 us; speedup vs baseline: 2.6307x; 2.6307x over previous
//
#include <hip/hip_runtime.h>
#include <hip/hip_bf16.h>
#include <math.h>

// ---- problem constants ----
#define B_SZ     2
#define SEQ      4096
#define DMODEL   1024
#define DSTATE   128
#define HEADDIM  64
#define CHUNK    256
#define DINNER   2048
#define DSSM     2048
#define NHEADS   32
#define CONVDIM  2304       // DSSM + 2*DSTATE
#define DOUTSZ   1024
#define NC       16         // SEQ / CHUNK
#define EPSF     1e-5f

typedef __hip_bfloat16 bf16;
typedef __attribute__((ext_vector_type(8))) short bf16x8;
typedef __attribute__((ext_vector_type(4))) float f32x4;

__device__ __forceinline__ float siluf(float x) { return x / (1.0f + expf(-x)); }

__device__ __forceinline__ float bfu(unsigned short u) {
    union { unsigned int i; float f; } c; c.i = ((unsigned int)u) << 16; return c.f;
}
__device__ __forceinline__ unsigned short f2bf(float f) {
    union { float f; unsigned int u; } c; c.f = f;
    unsigned int u = c.u;
    return (unsigned short)((u + 0x7FFFu + ((u >> 16) & 1u)) >> 16);
}

// 4-element contiguous load -> fp32
__device__ __forceinline__ void ld4(const float* p, float* d) {
    float4 v = *(const float4*)p; d[0] = v.x; d[1] = v.y; d[2] = v.z; d[3] = v.w;
}
__device__ __forceinline__ void ld4(const bf16* p, float* d) {
    ushort4 v = *(const ushort4*)(const void*)p;
    d[0] = bfu(v.x); d[1] = bfu(v.y); d[2] = bfu(v.z); d[3] = bfu(v.w);
}
__device__ __forceinline__ void stc(float* p, float v) { *p = v; }
__device__ __forceinline__ void stc(bf16* p, float v) { *p = __float2bfloat16(v); }

// async global(16B) -> LDS (wave-uniform base + lane*16)
__device__ __forceinline__ void gload16(const void* g, void* l) {
    typedef __attribute__((address_space(1))) const unsigned int GU;
    typedef __attribute__((address_space(3))) unsigned int LU;
    __builtin_amdgcn_global_load_lds((GU*)g, (LU*)l, 16, 0, 0);
}

// ============================================================
// fp32 -> bf16 cast, 8 elems/thread
// ============================================================
__global__ __launch_bounds__(256)
void cast_f32_bf16(const float* __restrict__ src, unsigned short* __restrict__ dst)
{
    const long long i = ((long long)blockIdx.x * 256 + threadIdx.x) * 8;
    float4 a = *(const float4*)(src + i);
    float4 b = *(const float4*)(src + i + 4);
    bf16x8 o;
    o[0] = (short)f2bf(a.x); o[1] = (short)f2bf(a.y);
    o[2] = (short)f2bf(a.z); o[3] = (short)f2bf(a.w);
    o[4] = (short)f2bf(b.x); o[5] = (short)f2bf(b.y);
    o[6] = (short)f2bf(b.z); o[7] = (short)f2bf(b.w);
    *(bf16x8*)(dst + i) = o;
}

// ============================================================
// bf16 MFMA NT GEMM: C[m,n] = sum_k A[m][k]*B[n][k]
// A[M][K], B[N][K] bf16 (as short). 128x128 tile, BK=32, 4 waves.
// LDS slot layout: slot = kg*128 + row (16B = 8 bf16 of row at k-group kg)
// M,N multiples of 128, K multiple of 32.
// ============================================================
template<typename TC>
__global__ __launch_bounds__(256)
void gemm_mfma_nt(const short* __restrict__ A, const short* __restrict__ B,
                  TC* __restrict__ C, int M, int N, int K)
{
    __shared__ short As[128 * 32];
    __shared__ short Bs[128 * 32];

    const int tid  = threadIdx.x;
    const int lane = tid & 63;
    const int wid  = tid >> 6;
    const int m0 = blockIdx.y * 128;
    const int n0 = blockIdx.x * 128;
    const int wr = (wid >> 1) * 64;   // wave row origin in tile
    const int wc = (wid & 1) * 64;    // wave col origin in tile

    // staging source: thread handles slots tid (round 0) and tid+256 (round 1)
    const int srow = tid & 127;
    const int skg  = tid >> 7;                 // 0 or 1; round1 kg = skg+2
    const short* Ag = A + (long long)(m0 + srow) * K + skg * 8;
    const short* Bg = B + (long long)(n0 + srow) * K + skg * 8;
    short* AsW0 = &As[(wid * 64) * 8];         // wave-uniform LDS bases
    short* AsW1 = &As[(256 + wid * 64) * 8];
    short* BsW0 = &Bs[(wid * 64) * 8];
    short* BsW1 = &Bs[(256 + wid * 64) * 8];

    // fragment read offsets
    const int frow = lane & 15;
    const int fk   = lane >> 4;     // 0..3

    f32x4 acc[4][4];
    #pragma unroll
    for (int i = 0; i < 4; ++i)
        #pragma unroll
        for (int j = 0; j < 4; ++j) acc[i][j] = (f32x4)(0.0f);

    for (int k0 = 0; k0 < K; k0 += 32) {
        gload16(Ag + k0,      AsW0);
        gload16(Ag + k0 + 16, AsW1);
        gload16(Bg + k0,      BsW0);
        gload16(Bg + k0 + 16, BsW1);
        __syncthreads();

        bf16x8 a[4], b[4];
        #pragma unroll
        for (int fm = 0; fm < 4; ++fm)
            a[fm] = *(const bf16x8*)&As[(fk * 128 + wr + fm * 16 + frow) * 8];
        #pragma unroll
        for (int fn = 0; fn < 4; ++fn)
            b[fn] = *(const bf16x8*)&Bs[(fk * 128 + wc + fn * 16 + frow) * 8];
        #pragma unroll
        for (int fm = 0; fm < 4; ++fm)
            #pragma unroll
            for (int fn = 0; fn < 4; ++fn)
                acc[fm][fn] = __builtin_amdgcn_mfma_f32_16x16x32_bf16(
                    a[fm], b[fn], acc[fm][fn], 0, 0, 0);
        __syncthreads();
    }

    // epilogue: col = lane&15, row = (lane>>4)*4 + j
    const int crow = (lane >> 4) * 4;
    const int ccol = lane & 15;
    #pragma unroll
    for (int fm = 0; fm < 4; ++fm) {
        #pragma unroll
        for (int j = 0; j < 4; ++j) {
            long long row = m0 + wr + fm * 16 + crow + j;
            TC* cp = C + row * N + n0 + wc + ccol;
            #pragma unroll
            for (int fn = 0; fn < 4; ++fn) {
                float v = acc[fm][fn][j];
                if constexpr (sizeof(TC) == 2) cp[fn * 16] = (TC)f2bf(v);
                else                           cp[fn * 16] = v;
            }
        }
    }
}

// ============================================================
// Generic fp32 NT GEMM (kept for dt column + chunk-S batched GEMM)
// ============================================================
#define BM 64
#define BN 64
#define BKK 16

template<typename TA, typename TC>
__global__ __launch_bounds__(256)
void gemm_nt(const TA* __restrict__ A, const float* __restrict__ B,
             TC* __restrict__ C, int M, int N, int K,
             int lda, int ldb, int ldc,
             long long sA, long long sB, long long sC)
{
    A += (long long)blockIdx.z * sA;
    B += (long long)blockIdx.z * sB;
    C += (long long)blockIdx.z * sC;

    __shared__ float As[BM][BKK + 1];
    __shared__ float Bs[BN][BKK + 1];

    const int tid = threadIdx.x;
    const int tx = tid & 15;
    const int ty = tid >> 4;
    const int m0 = blockIdx.y * BM;
    const int n0 = blockIdx.x * BN;

    const int lrow = tid >> 2;
    const int lk4  = (tid & 3) * 4;

    float acc[4][4] = {};

    for (int k0 = 0; k0 < K; k0 += BKK) {
        {
            int gm = m0 + lrow;
            float v[4] = {0.f, 0.f, 0.f, 0.f};
            if (gm < M) ld4(A + (long long)gm * lda + k0 + lk4, v);
            As[lrow][lk4 + 0] = v[0]; As[lrow][lk4 + 1] = v[1];
            As[lrow][lk4 + 2] = v[2]; As[lrow][lk4 + 3] = v[3];
        }
        {
            int gn = n0 + lrow;
            float v[4] = {0.f, 0.f, 0.f, 0.f};
            if (gn < N) ld4(B + (long long)gn * ldb + k0 + lk4, v);
            Bs[lrow][lk4 + 0] = v[0]; Bs[lrow][lk4 + 1] = v[1];
            Bs[lrow][lk4 + 2] = v[2]; Bs[lrow][lk4 + 3] = v[3];
        }
        __syncthreads();
        #pragma unroll
        for (int kk = 0; kk < BKK; ++kk) {
            float a[4], b[4];
            #pragma unroll
            for (int i = 0; i < 4; ++i) a[i] = As[ty * 4 + i][kk];
            #pragma unroll
            for (int j = 0; j < 4; ++j) b[j] = Bs[tx * 4 + j][kk];
            #pragma unroll
            for (int i = 0; i < 4; ++i)
                #pragma unroll
                for (int j = 0; j < 4; ++j)
                    acc[i][j] += a[i] * b[j];
        }
        __syncthreads();
    }
    #pragma unroll
    for (int i = 0; i < 4; ++i) {
        int gm = m0 + ty * 4 + i;
        if (gm >= M) continue;
        #pragma unroll
        for (int j = 0; j < 4; ++j) {
            int gn = n0 + tx * 4 + j;
            if (gn < N) stc(&C[(long long)gm * ldc + gn], acc[i][j]);
        }
    }
}

// ============================================================
// Depthwise causal conv (width 4) + bias + SiLU over xBC, split outputs.
// ============================================================
__global__ __launch_bounds__(256)
void conv_silu(const bf16* __restrict__ xbc, const float* __restrict__ cw,
               const float* __restrict__ cb,
               bf16* __restrict__ xconv, float* __restrict__ Bc,
               float* __restrict__ Cc)
{
    const int tid = threadIdx.x;
    const int c  = (blockIdx.x % 9) * 256 + tid;
    const int lf = blockIdx.x / 9;
    const int b  = lf / SEQ;
    const int l  = lf % SEQ;

    float acc = cb[c];
    #pragma unroll
    for (int k = 0; k < 4; ++k) {
        int ls = l - 3 + k;
        if (ls >= 0)
            acc += __bfloat162float(xbc[((long long)(b * SEQ + ls)) * CONVDIM + c]) * cw[c * 4 + k];
    }
    float v = siluf(acc);
    if (c < DSSM)
        xconv[(long long)lf * DSSM + c] = __float2bfloat16(v);
    else if (c < DSSM + DSTATE)
        Bc[(long long)lf * DSTATE + (c - DSSM)] = v;
    else
        Cc[(long long)lf * DSTATE + (c - DSSM - DSTATE)] = v;
}

// ============================================================
__global__ __launch_bounds__(256)
void dtproj(const float* __restrict__ dtraw, const float* __restrict__ dt_bias,
            float* __restrict__ dtp)
{
    int f = blockIdx.x * 256 + threadIdx.x;
    int h = f & 31;
    float x = dtraw[f] + dt_bias[h];
    dtp[f] = (x > 20.f) ? x : log1pf(expf(x));
}

// ============================================================
__global__ __launch_bounds__(256)
void cumsum_da(const float* __restrict__ dtp, const float* __restrict__ A_log,
               float* __restrict__ cs)
{
    const int bid = blockIdx.x;
    const int z = bid % NC;
    const int h = (bid / NC) % NHEADS;
    const int b = bid / (NC * NHEADS);
    const int t = threadIdx.x;

    const float Ah = -expf(A_log[h]);
    const int lg = z * CHUNK + t;
    float v = dtp[((long long)(b * SEQ) + lg) * NHEADS + h] * Ah;

    __shared__ float s[CHUNK];
    s[t] = v;
    __syncthreads();
    for (int off = 1; off < CHUNK; off <<= 1) {
        float add = (t >= off) ? s[t - off] : 0.f;
        __syncthreads();
        s[t] += add;
        __syncthreads();
    }
    cs[((long long)(b * NHEADS) + h) * SEQ + lg] = s[t];
}

// ============================================================
// Y_diag: per (b,z,h) block. y[l,p] = sum_{s<=l} S[l,s]*exp(cs_l-cs_s)*xd[s,p]
// ============================================================
__global__ __launch_bounds__(256)
void ydiag(const bf16* __restrict__ S, const bf16* __restrict__ xconv,
           const float* __restrict__ dtp, const float* __restrict__ cs,
           bf16* __restrict__ y)
{
    const int h  = blockIdx.x % NHEADS;
    const int bz = blockIdx.x / NHEADS;
    const int z  = bz % NC;
    const int b  = bz / NC;
    const int l  = threadIdx.x;

    __shared__ float Ss[CHUNK][17];
    __shared__ float xds[16][HEADDIM];
    __shared__ float css[CHUNK];

    const bf16* Sb = S + (long long)bz * CHUNK * CHUNK;
    const long long rowbase = (long long)b * SEQ + (long long)z * CHUNK;

    css[l] = cs[((long long)(b * NHEADS) + h) * SEQ + z * CHUNK + l];

    float acc[HEADDIM];
    #pragma unroll
    for (int p = 0; p < HEADDIM; ++p) acc[p] = 0.f;
    __syncthreads();
    const float cl = css[l];

    for (int s0 = 0; s0 < CHUNK; s0 += 16) {
        #pragma unroll
        for (int j = 0; j < 16; ++j) {
            int flat = j * 256 + threadIdx.x;
            int row = flat >> 4, sc = flat & 15;
            Ss[row][sc] = __bfloat162float(Sb[row * CHUNK + s0 + sc]);
        }
        {
            int p  = threadIdx.x & 63;
            int sl = threadIdx.x >> 6;
            #pragma unroll
            for (int j = 0; j < 4; ++j) {
                int s = s0 + sl + j * 4;
                long long lg = rowbase + s;
                xds[sl + j * 4][p] =
                    __bfloat162float(xconv[lg * DSSM + h * 64 + p]) * dtp[lg * NHEADS + h];
            }
        }
        __syncthreads();
        int smax = l - s0 + 1;
        if (smax > 16) smax = 16;
        for (int sl = 0; sl < smax; ++sl) {
            float w = Ss[l][sl] * expf(cl - css[s0 + sl]);
            #pragma unroll
            for (int p = 0; p < HEADDIM; p += 4) {
                float4 xv = *(const float4*)&xds[sl][p];
                acc[p + 0] += w * xv.x; acc[p + 1] += w * xv.y;
                acc[p + 2] += w * xv.z; acc[p + 3] += w * xv.w;
            }
        }
        __syncthreads();
    }
    bf16* outr = y + (rowbase + l) * DSSM + h * 64;
    #pragma unroll
    for (int p = 0; p < HEADDIM; ++p)
        outr[p] = __float2bfloat16(acc[p]);
}

// ============================================================
// states[p,n] = sum_l Bm[l,n]*exp(cs_last-cs_l)*xd[l,p]  per (b,z,h)
// ============================================================
__global__ __launch_bounds__(256)
void chunk_states(const float* __restrict__ Bcp, const bf16* __restrict__ xconv,
                  const float* __restrict__ dtp, const float* __restrict__ cs,
                  float* __restrict__ states)
{
    const int h  = blockIdx.x % NHEADS;
    const int bz = blockIdx.x / NHEADS;
    const int z  = bz % NC;
    const int b  = bz / NC;
    const int tid = threadIdx.x;

    __shared__ float Bd[16][DSTATE];
    __shared__ float xdt[16][HEADDIM];
    __shared__ float css[CHUNK];
    __shared__ float dec[CHUNK];

    css[tid] = cs[((long long)(b * NHEADS) + h) * SEQ + z * CHUNK + tid];
    __syncthreads();
    const float cslast = css[CHUNK - 1];
    dec[tid] = expf(cslast - css[tid]);
    __syncthreads();

    const int tx = tid & 31;
    const int ty = tid >> 5;
    const long long rowbase = (long long)b * SEQ + (long long)z * CHUNK;

    float acc[8][4] = {};

    for (int l0 = 0; l0 < CHUNK; l0 += 16) {
        #pragma unroll
        for (int j = 0; j < 8; ++j) {
            int flat = j * 256 + tid;
            int ll = flat >> 7, n = flat & 127;
            int lg = l0 + ll;
            Bd[ll][n] = Bcp[(rowbase + lg) * DSTATE + n] * dec[lg];
        }
        #pragma unroll
        for (int j = 0; j < 4; ++j) {
            int flat = j * 256 + tid;
            int ll = flat >> 6, p = flat & 63;
            int lg = l0 + ll;
            xdt[ll][p] = __bfloat162float(xconv[(rowbase + lg) * DSSM + h * 64 + p])
                       * dtp[(rowbase + lg) * NHEADS + h];
        }
        __syncthreads();
        #pragma unroll
        for (int ll = 0; ll < 16; ++ll) {
            float bv[4];
            #pragma unroll
            for (int j = 0; j < 4; ++j) bv[j] = Bd[ll][tx * 4 + j];
            #pragma unroll
            for (int i = 0; i < 8; ++i) {
                float a = xdt[ll][ty * 8 + i];
                #pragma unroll
                for (int j = 0; j < 4; ++j) acc[i][j] += a * bv[j];
            }
        }
        __syncthreads();
    }
    float* st = states + ((long long)(bz * NHEADS + h)) * HEADDIM * DSTATE;
    #pragma unroll
    for (int i = 0; i < 8; ++i) {
        int p = ty * 8 + i;
        float4 v = make_float4(acc[i][0], acc[i][1], acc[i][2], acc[i][3]);
        *(float4*)(st + p * DSTATE + tx * 4) = v;
    }
}

// ============================================================
__global__ __launch_bounds__(256)
void chunk_scan(float* __restrict__ states, const float* __restrict__ cs)
{
    int f = blockIdx.x * 256 + threadIdx.x;
    int n = f & 127;
    int p = (f >> 7) & 63;
    int h = (f >> 13) & 31;
    int b = f >> 18;

    float carry = 0.f;
    for (int z = 0; z < NC; ++z) {
        long long idx = ((((long long)(b * NC + z) * NHEADS) + h) * HEADDIM + p) * DSTATE + n;
        float st = states[idx];
        states[idx] = carry;
        float cd = expf(cs[((long long)(b * NHEADS) + h) * SEQ + z * CHUNK + CHUNK - 1]);
        carry = carry * cd + st;
    }
}

// ============================================================
__global__ __launch_bounds__(256)
void yoff_combine(const float* __restrict__ Cc, const float* __restrict__ prev,
                  const bf16* __restrict__ xconv, const float* __restrict__ cs,
                  const float* __restrict__ Dv, bf16* __restrict__ y)
{
    const int h  = blockIdx.x % NHEADS;
    const int bz = blockIdx.x / NHEADS;
    const int z  = bz % NC;
    const int b  = bz / NC;
    const int tid = threadIdx.x;
    const int l = tid;

    __shared__ float prevS[HEADDIM][DSTATE];
    __shared__ float Cst[CHUNK][17];
    __shared__ float css[CHUNK];

    const float* pv = prev + (long long)(bz * NHEADS + h) * HEADDIM * DSTATE;
    #pragma unroll
    for (int j = 0; j < 32; ++j) {
        int flat = j * 256 + tid;
        prevS[flat >> 7][flat & 127] = pv[flat];
    }
    css[tid] = cs[((long long)(b * NHEADS) + h) * SEQ + z * CHUNK + tid];
    __syncthreads();

    const long long rowbase = (long long)b * SEQ + (long long)z * CHUNK;
    float acc[HEADDIM];
    #pragma unroll
    for (int p = 0; p < HEADDIM; ++p) acc[p] = 0.f;

    for (int n0 = 0; n0 < DSTATE; n0 += 16) {
        #pragma unroll
        for (int j = 0; j < 16; ++j) {
            int flat = j * 256 + tid;
            int row = flat >> 4, nc2 = flat & 15;
            Cst[row][nc2] = Cc[(rowbase + row) * DSTATE + n0 + nc2];
        }
        __syncthreads();
        float cv[16];
        #pragma unroll
        for (int nl = 0; nl < 16; ++nl) cv[nl] = Cst[l][nl];
        #pragma unroll
        for (int p = 0; p < HEADDIM; ++p) {
            #pragma unroll
            for (int q = 0; q < 16; q += 4) {
                float4 pr = *(const float4*)&prevS[p][n0 + q];
                acc[p] += cv[q + 0] * pr.x + cv[q + 1] * pr.y
                        + cv[q + 2] * pr.z + cv[q + 3] * pr.w;
            }
        }
        __syncthreads();
    }
    const float el = expf(css[l]);
    const float Dh = Dv[h];
    bf16* yr = y + (rowbase + l) * DSSM + h * 64;
    const bf16* xr = xconv + (rowbase + l) * DSSM + h * 64;
    #pragma unroll
    for (int p = 0; p < HEADDIM; ++p) {
        float yd = __bfloat162float(yr[p]);
        float xv = __bfloat162float(xr[p]);
        yr[p] = __float2bfloat16(yd + el * acc[p] + Dh * xv);
    }
}

// ============================================================
__global__ __launch_bounds__(256)
void gated_rmsnorm(bf16* __restrict__ y, const bf16* __restrict__ z,
                   const float* __restrict__ nw)
{
    const int row = blockIdx.x;
    const int tid = threadIdx.x;
    bf16* yr = y + (long long)row * DSSM;
    const bf16* zr = z + (long long)row * DSSM;

    float t[8];
    float ss = 0.f;
    const int c0 = tid * 8;
    #pragma unroll
    for (int j = 0; j < 8; ++j) {
        float zv = __bfloat162float(zr[c0 + j]);
        float tv = __bfloat162float(yr[c0 + j]) * siluf(zv);
        t[j] = tv;
        ss += tv * tv;
    }
    #pragma unroll
    for (int off = 32; off > 0; off >>= 1) ss += __shfl_down(ss, off);
    __shared__ float red[4];
    if ((tid & 63) == 0) red[tid >> 6] = ss;
    __syncthreads();
    float tot = red[0] + red[1] + red[2] + red[3];
    float rs = rsqrtf(tot / (float)DSSM + EPSF);
    #pragma unroll
    for (int j = 0; j < 8; ++j)
        yr[c0 + j] = __float2bfloat16(t[j] * rs * nw[c0 + j]);
}

// ============================================================
extern "C" void kernel_launch(void* const* d_in, const int* in_sizes, int n_in,
                              void* d_out, int out_size, void* d_ws, size_t ws_size,
                              hipStream_t stream)
{
    const float* inp     = (const float*)d_in[0];
    const float* W_in    = (const float*)d_in[1];
    const float* conv_w  = (const float*)d_in[2];
    const float* conv_b  = (const float*)d_in[3];
    const float* dt_bias = (const float*)d_in[4];
    const float* A_log   = (const float*)d_in[5];
    const float* Dv      = (const float*)d_in[6];
    const float* norm_w  = (const float*)d_in[7];
    const float* W_out   = (const float*)d_in[8];
    float* out = (float*)d_out;

    char* ws = (char*)d_ws;
    size_t off = 0;
    auto alloc = [&](size_t bytes) -> void* {
        void* p = (void*)(ws + off);
        off = (off + bytes + 255) & ~(size_t)255;
        return p;
    };
    const int MR = B_SZ * SEQ;   // 8192 token rows

    bf16*  zb     = (bf16*) alloc((size_t)MR * DSSM * 2);            // 33.55 MB (to rmsnorm)
    bf16*  xbc    = (bf16*) alloc((size_t)MR * CONVDIM * 2);         // 37.75 MB (dead after conv)
    bf16*  xconv  = (bf16*) alloc((size_t)MR * DSSM * 2);            // 33.55 MB
    float* Bc     = (float*)alloc((size_t)MR * DSTATE * 4);          // 4.19 MB
    float* Cc     = (float*)alloc((size_t)MR * DSTATE * 4);          // 4.19 MB
    float* dtraw  = (float*)alloc((size_t)MR * NHEADS * 4);          // 1.05 MB
    float* dtp    = (float*)alloc((size_t)MR * NHEADS * 4);          // 1.05 MB
    float* cs     = (float*)alloc((size_t)B_SZ * NHEADS * SEQ * 4);  // 1.05 MB
    float* states = (float*)alloc((size_t)B_SZ * NC * NHEADS * HEADDIM * DSTATE * 4); // 33.55 MB
    unsigned short* Wob = (unsigned short*)alloc((size_t)DOUTSZ * DINNER * 2);        // 4.19 MB

    // aliases (lifetime-disjoint, stream-ordered):
    // Smat + ybuf into dead xbc region
    bf16*  Smat   = (bf16*)xbc;
    bf16*  ybuf   = (bf16*)((char*)xbc + (size_t)B_SZ * NC * CHUNK * CHUNK * 2);
    // bf16 input overlays states (inpb dead before states written)
    unsigned short* inpb = (unsigned short*)states;                  // 16.78 MB
    // bf16 W_in overlays Bc..dtraw (Wb dead before conv writes Bc/Cc; dt gemm
    // writes dtraw only after both MFMA gemms that read Wb have completed)
    unsigned short* Wb = (unsigned short*)Bc;                        // 8.98 MB

    dim3 blk(256);

    // 0) casts to bf16
    cast_f32_bf16<<<dim3((MR * DMODEL) / (256 * 8)), blk, 0, stream>>>(inp, inpb);
    cast_f32_bf16<<<dim3((4384 * DMODEL) / (256 * 8)), blk, 0, stream>>>(W_in, Wb);
    cast_f32_bf16<<<dim3((DOUTSZ * DINNER) / (256 * 8)), blk, 0, stream>>>(W_out, Wob);

    // 1) in_proj: z (N=2048) and xBC (N=2304) via bf16 MFMA; dt (N=32) fp32
    gemm_mfma_nt<unsigned short><<<dim3(DSSM / 128, MR / 128), blk, 0, stream>>>(
        (const short*)inpb, (const short*)Wb, (unsigned short*)zb, MR, DSSM, DMODEL);
    gemm_mfma_nt<unsigned short><<<dim3(CONVDIM / 128, MR / 128), blk, 0, stream>>>(
        (const short*)inpb, (const short*)(Wb + (size_t)DSSM * DMODEL),
        (unsigned short*)xbc, MR, CONVDIM, DMODEL);
    gemm_nt<float, float><<<dim3(1, MR / BM, 1), blk, 0, stream>>>(
        inp, W_in + (size_t)(DSSM + CONVDIM) * DMODEL, dtraw,
        MR, NHEADS, DMODEL, DMODEL, DMODEL, NHEADS, 0, 0, 0);

    // 2) conv + silu + split (xbc dead afterwards)
    conv_silu<<<dim3(MR * 9), blk, 0, stream>>>(xbc, conv_w, conv_b, xconv, Bc, Cc);

    // 3) dtp = softplus(dt_raw + dt_bias)
    dtproj<<<dim3(MR * NHEADS / 256), blk, 0, stream>>>(dtraw, dt_bias, dtp);

    // 4) cumsum of dA per (b,h,chunk)
    cumsum_da<<<dim3(B_SZ * NHEADS * NC), blk, 0, stream>>>(dtp, A_log, cs);

    // 5) S = Cm @ Bm^T per (b,chunk) -> bf16 Smat (aliases xbc)
    gemm_nt<float, bf16><<<dim3(CHUNK / BN, CHUNK / BM, B_SZ * NC), blk, 0, stream>>>(
        Cc, Bc, Smat, CHUNK, CHUNK, DSTATE, DSTATE, DSTATE, CHUNK,
        (long long)CHUNK * DSTATE, (long long)CHUNK * DSTATE, (long long)CHUNK * CHUNK);

    // 6) Y_diag -> ybuf
    ydiag<<<dim3(B_SZ * NC * NHEADS), blk, 0, stream>>>(Smat, xconv, dtp, cs, ybuf);

    // 7) per-chunk states (states overlays inpb -- inpb dead after step 1)
    chunk_states<<<dim3(B_SZ * NC * NHEADS), blk, 0, stream>>>(Bc, xconv, dtp, cs, states);

    // 8) inter-chunk scan (in place -> prev)
    chunk_scan<<<dim3(B_SZ * NHEADS * HEADDIM * DSTATE / 256), blk, 0, stream>>>(states, cs);

    // 9) Y_off + D*x combine
    yoff_combine<<<dim3(B_SZ * NC * NHEADS), blk, 0, stream>>>(Cc, states, xconv, cs, Dv, ybuf);

    // 10) gated RMSNorm (in place on ybuf)
    gated_rmsnorm<<<dim3(MR), blk, 0, stream>>>(ybuf, zb, norm_w);

    // 11) out GEMM: out = ybuf @ W_out^T  (bf16 MFMA, fp32 out)
    gemm_mfma_nt<float><<<dim3(DOUTSZ / 128, MR / 128), blk, 0, stream>>>(
        (const short*)ybuf, (const short*)Wob, out, MR, DOUTSZ, DINNER);
}

// Round 4
// 594.043 us; speedup vs baseline: 4.8526x; 1.8447x over previous
//
#include <hip/hip_runtime.h>
#include <hip/hip_bf16.h>
#include <math.h>

// ---- problem constants ----
#define B_SZ     2
#define SEQ      4096
#define DMODEL   1024
#define DSTATE   128
#define HEADDIM  64
#define CHUNK    256
#define DINNER   2048
#define DSSM     2048
#define NHEADS   32
#define CONVDIM  2304       // DSSM + 2*DSTATE
#define DOUTSZ   1024
#define NC       16         // SEQ / CHUNK
#define EPSF     1e-5f

typedef __hip_bfloat16 bf16;
typedef __attribute__((ext_vector_type(8))) short bf16x8;
typedef __attribute__((ext_vector_type(4))) float f32x4;

__device__ __forceinline__ float siluf(float x) { return x / (1.0f + expf(-x)); }

__device__ __forceinline__ float bfu(unsigned short u) {
    union { unsigned int i; float f; } c; c.i = ((unsigned int)u) << 16; return c.f;
}
__device__ __forceinline__ unsigned short f2bf(float f) {
    union { float f; unsigned int u; } c; c.f = f;
    unsigned int u = c.u;
    return (unsigned short)((u + 0x7FFFu + ((u >> 16) & 1u)) >> 16);
}

__device__ __forceinline__ void ld4(const float* p, float* d) {
    float4 v = *(const float4*)p; d[0] = v.x; d[1] = v.y; d[2] = v.z; d[3] = v.w;
}
__device__ __forceinline__ void stc(float* p, float v) { *p = v; }

// async global(16B) -> LDS (wave-uniform base + lane*16)
__device__ __forceinline__ void gload16(const void* g, void* l) {
    typedef __attribute__((address_space(1))) const unsigned int GU;
    typedef __attribute__((address_space(3))) unsigned int LU;
    __builtin_amdgcn_global_load_lds((GU*)g, (LU*)l, 16, 0, 0);
}

// ============================================================
// fp32 -> bf16 cast, 8 elems/thread
// ============================================================
__global__ __launch_bounds__(256)
void cast_f32_bf16(const float* __restrict__ src, unsigned short* __restrict__ dst)
{
    const long long i = ((long long)blockIdx.x * 256 + threadIdx.x) * 8;
    float4 a = *(const float4*)(src + i);
    float4 b = *(const float4*)(src + i + 4);
    bf16x8 o;
    o[0] = (short)f2bf(a.x); o[1] = (short)f2bf(a.y);
    o[2] = (short)f2bf(a.z); o[3] = (short)f2bf(a.w);
    o[4] = (short)f2bf(b.x); o[5] = (short)f2bf(b.y);
    o[6] = (short)f2bf(b.z); o[7] = (short)f2bf(b.w);
    *(bf16x8*)(dst + i) = o;
}

// ============================================================
// bf16 MFMA NT GEMM: C[m,n] = sum_k A[m][k]*B[n][k]
// 128x128 tile, BK=32, 4 waves. Batched via blockIdx.z (element strides).
// M,N multiples of 128, K multiple of 32.
// ============================================================
template<typename TC>
__global__ __launch_bounds__(256)
void gemm_mfma_nt(const short* __restrict__ A, const short* __restrict__ B,
                  TC* __restrict__ C, int M, int N, int K,
                  long long sA, long long sB, long long sC)
{
    A += (long long)blockIdx.z * sA;
    B += (long long)blockIdx.z * sB;
    C += (long long)blockIdx.z * sC;

    __shared__ short As[128 * 32];
    __shared__ short Bs[128 * 32];

    const int tid  = threadIdx.x;
    const int lane = tid & 63;
    const int wid  = tid >> 6;
    const int m0 = blockIdx.y * 128;
    const int n0 = blockIdx.x * 128;
    const int wr = (wid >> 1) * 64;
    const int wc = (wid & 1) * 64;

    const int srow = tid & 127;
    const int skg  = tid >> 7;
    const short* Ag = A + (long long)(m0 + srow) * K + skg * 8;
    const short* Bg = B + (long long)(n0 + srow) * K + skg * 8;
    short* AsW0 = &As[(wid * 64) * 8];
    short* AsW1 = &As[(256 + wid * 64) * 8];
    short* BsW0 = &Bs[(wid * 64) * 8];
    short* BsW1 = &Bs[(256 + wid * 64) * 8];

    const int frow = lane & 15;
    const int fk   = lane >> 4;

    f32x4 acc[4][4];
    #pragma unroll
    for (int i = 0; i < 4; ++i)
        #pragma unroll
        for (int j = 0; j < 4; ++j) acc[i][j] = (f32x4)(0.0f);

    for (int k0 = 0; k0 < K; k0 += 32) {
        gload16(Ag + k0,      AsW0);
        gload16(Ag + k0 + 16, AsW1);
        gload16(Bg + k0,      BsW0);
        gload16(Bg + k0 + 16, BsW1);
        __syncthreads();

        bf16x8 a[4], b[4];
        #pragma unroll
        for (int fm = 0; fm < 4; ++fm)
            a[fm] = *(const bf16x8*)&As[(fk * 128 + wr + fm * 16 + frow) * 8];
        #pragma unroll
        for (int fn = 0; fn < 4; ++fn)
            b[fn] = *(const bf16x8*)&Bs[(fk * 128 + wc + fn * 16 + frow) * 8];
        #pragma unroll
        for (int fm = 0; fm < 4; ++fm)
            #pragma unroll
            for (int fn = 0; fn < 4; ++fn)
                acc[fm][fn] = __builtin_amdgcn_mfma_f32_16x16x32_bf16(
                    a[fm], b[fn], acc[fm][fn], 0, 0, 0);
        __syncthreads();
    }

    const int crow = (lane >> 4) * 4;
    const int ccol = lane & 15;
    #pragma unroll
    for (int fm = 0; fm < 4; ++fm) {
        #pragma unroll
        for (int j = 0; j < 4; ++j) {
            long long row = m0 + wr + fm * 16 + crow + j;
            TC* cp = C + row * N + n0 + wc + ccol;
            #pragma unroll
            for (int fn = 0; fn < 4; ++fn) {
                float v = acc[fm][fn][j];
                if constexpr (sizeof(TC) == 2) cp[fn * 16] = (TC)f2bf(v);
                else                           cp[fn * 16] = v;
            }
        }
    }
}

// ============================================================
// fp32 NT GEMM (kept only for the small dt column)
// ============================================================
#define BM 64
#define BN 64
#define BKK 16

__global__ __launch_bounds__(256)
void gemm_nt(const float* __restrict__ A, const float* __restrict__ B,
             float* __restrict__ C, int M, int N, int K,
             int lda, int ldb, int ldc)
{
    __shared__ float As[BM][BKK + 1];
    __shared__ float Bs[BN][BKK + 1];

    const int tid = threadIdx.x;
    const int tx = tid & 15;
    const int ty = tid >> 4;
    const int m0 = blockIdx.y * BM;
    const int n0 = blockIdx.x * BN;

    const int lrow = tid >> 2;
    const int lk4  = (tid & 3) * 4;

    float acc[4][4] = {};

    for (int k0 = 0; k0 < K; k0 += BKK) {
        {
            int gm = m0 + lrow;
            float v[4] = {0.f, 0.f, 0.f, 0.f};
            if (gm < M) ld4(A + (long long)gm * lda + k0 + lk4, v);
            As[lrow][lk4 + 0] = v[0]; As[lrow][lk4 + 1] = v[1];
            As[lrow][lk4 + 2] = v[2]; As[lrow][lk4 + 3] = v[3];
        }
        {
            int gn = n0 + lrow;
            float v[4] = {0.f, 0.f, 0.f, 0.f};
            if (gn < N) ld4(B + (long long)gn * ldb + k0 + lk4, v);
            Bs[lrow][lk4 + 0] = v[0]; Bs[lrow][lk4 + 1] = v[1];
            Bs[lrow][lk4 + 2] = v[2]; Bs[lrow][lk4 + 3] = v[3];
        }
        __syncthreads();
        #pragma unroll
        for (int kk = 0; kk < BKK; ++kk) {
            float a[4], b[4];
            #pragma unroll
            for (int i = 0; i < 4; ++i) a[i] = As[ty * 4 + i][kk];
            #pragma unroll
            for (int j = 0; j < 4; ++j) b[j] = Bs[tx * 4 + j][kk];
            #pragma unroll
            for (int i = 0; i < 4; ++i)
                #pragma unroll
                for (int j = 0; j < 4; ++j)
                    acc[i][j] += a[i] * b[j];
        }
        __syncthreads();
    }
    #pragma unroll
    for (int i = 0; i < 4; ++i) {
        int gm = m0 + ty * 4 + i;
        if (gm >= M) continue;
        #pragma unroll
        for (int j = 0; j < 4; ++j) {
            int gn = n0 + tx * 4 + j;
            if (gn < N) C[(long long)gm * ldc + gn] = acc[i][j];
        }
    }
}

// ============================================================
// Depthwise causal conv (width 4) + bias + SiLU; Bc/Cc now bf16.
// ============================================================
__global__ __launch_bounds__(256)
void conv_silu(const bf16* __restrict__ xbc, const float* __restrict__ cw,
               const float* __restrict__ cb,
               bf16* __restrict__ xconv, bf16* __restrict__ Bc,
               bf16* __restrict__ Cc)
{
    const int tid = threadIdx.x;
    const int c  = (blockIdx.x % 9) * 256 + tid;
    const int lf = blockIdx.x / 9;
    const int b  = lf / SEQ;
    const int l  = lf % SEQ;

    float acc = cb[c];
    #pragma unroll
    for (int k = 0; k < 4; ++k) {
        int ls = l - 3 + k;
        if (ls >= 0)
            acc += __bfloat162float(xbc[((long long)(b * SEQ + ls)) * CONVDIM + c]) * cw[c * 4 + k];
    }
    float v = siluf(acc);
    if (c < DSSM)
        xconv[(long long)lf * DSSM + c] = __float2bfloat16(v);
    else if (c < DSSM + DSTATE)
        Bc[(long long)lf * DSTATE + (c - DSSM)] = __float2bfloat16(v);
    else
        Cc[(long long)lf * DSTATE + (c - DSSM - DSTATE)] = __float2bfloat16(v);
}

// ============================================================
__global__ __launch_bounds__(256)
void dtproj(const float* __restrict__ dtraw, const float* __restrict__ dt_bias,
            float* __restrict__ dtp)
{
    int f = blockIdx.x * 256 + threadIdx.x;
    int h = f & 31;
    float x = dtraw[f] + dt_bias[h];
    dtp[f] = (x > 20.f) ? x : log1pf(expf(x));
}

// ============================================================
__global__ __launch_bounds__(256)
void cumsum_da(const float* __restrict__ dtp, const float* __restrict__ A_log,
               float* __restrict__ cs)
{
    const int bid = blockIdx.x;
    const int z = bid % NC;
    const int h = (bid / NC) % NHEADS;
    const int b = bid / (NC * NHEADS);
    const int t = threadIdx.x;

    const float Ah = -expf(A_log[h]);
    const int lg = z * CHUNK + t;
    float v = dtp[((long long)(b * SEQ) + lg) * NHEADS + h] * Ah;

    __shared__ float s[CHUNK];
    s[t] = v;
    __syncthreads();
    for (int off = 1; off < CHUNK; off <<= 1) {
        float add = (t >= off) ? s[t - off] : 0.f;
        __syncthreads();
        s[t] += add;
        __syncthreads();
    }
    cs[((long long)(b * NHEADS) + h) * SEQ + lg] = s[t];
}

// ============================================================
// chunk_states (MFMA): states[p,n] = sum_l xd[l,p]*B[l,n]*dec[l]  per (b,z,h)
// A-op rows: xdT[p][l]; B-op rows: BdecT[n][l] (both transposed-staged, bf16)
// ============================================================
__global__ __launch_bounds__(256)
void chunk_states_mfma(const bf16* __restrict__ Bcp, const bf16* __restrict__ xconv,
                       const float* __restrict__ dtp, const float* __restrict__ cs,
                       float* __restrict__ states)
{
    const int h  = blockIdx.x & 31;
    const int bz = blockIdx.x >> 5;
    const int z  = bz & (NC - 1);
    const int b  = bz >> 4;
    const int tid = threadIdx.x;
    const int lane = tid & 63;
    const int wid = tid >> 6;
    const int frow = lane & 15;
    const int fk = lane >> 4;
    const int wn = wid * 32;

    __shared__ __attribute__((aligned(16))) short Xs[64][40];    // xdT
    __shared__ __attribute__((aligned(16))) short Bs2[128][40];  // BdecT
    __shared__ float dec[CHUNK];

    const long long csbase = ((long long)(b * NHEADS) + h) * SEQ + (long long)z * CHUNK;
    const long long rowbase = (long long)b * SEQ + (long long)z * CHUNK;
    {
        float cv = cs[csbase + tid];
        float cslast = cs[csbase + CHUNK - 1];
        dec[tid] = expf(cslast - cv);
    }
    __syncthreads();

    f32x4 acc[4][2];
    #pragma unroll
    for (int i = 0; i < 4; ++i) { acc[i][0] = (f32x4)(0.f); acc[i][1] = (f32x4)(0.f); }

    for (int l0 = 0; l0 < CHUNK; l0 += 32) {
        // stage xdT [64p][32l]
        {
            const int sl = tid >> 3;
            const int p8 = (tid & 7) * 8;
            long long r = rowbase + l0 + sl;
            const unsigned short* xp = (const unsigned short*)xconv + r * DSSM + h * 64 + p8;
            ushort4 a0 = *(const ushort4*)xp;
            ushort4 a1 = *(const ushort4*)(xp + 4);
            float sc_ = dtp[r * NHEADS + h];
            unsigned short t[8] = {a0.x,a0.y,a0.z,a0.w,a1.x,a1.y,a1.z,a1.w};
            #pragma unroll
            for (int j = 0; j < 8; ++j)
                Xs[p8 + j][sl] = (short)f2bf(bfu(t[j]) * sc_);
        }
        // stage BdecT [128n][32l]
        {
            const int ll = tid >> 3;
            const int n16 = (tid & 7) * 16;
            long long r = rowbase + l0 + ll;
            const unsigned short* bp = (const unsigned short*)Bcp + r * DSTATE + n16;
            float dv = dec[l0 + ll];
            #pragma unroll
            for (int g = 0; g < 4; ++g) {
                ushort4 v = *(const ushort4*)(bp + g * 4);
                Bs2[n16 + g * 4 + 0][ll] = (short)f2bf(bfu(v.x) * dv);
                Bs2[n16 + g * 4 + 1][ll] = (short)f2bf(bfu(v.y) * dv);
                Bs2[n16 + g * 4 + 2][ll] = (short)f2bf(bfu(v.z) * dv);
                Bs2[n16 + g * 4 + 3][ll] = (short)f2bf(bfu(v.w) * dv);
            }
        }
        __syncthreads();
        bf16x8 a[4], bb[2];
        #pragma unroll
        for (int fm = 0; fm < 4; ++fm)
            a[fm] = *(const bf16x8*)&Xs[fm * 16 + frow][fk * 8];
        #pragma unroll
        for (int fn = 0; fn < 2; ++fn)
            bb[fn] = *(const bf16x8*)&Bs2[wn + fn * 16 + frow][fk * 8];
        #pragma unroll
        for (int fm = 0; fm < 4; ++fm)
            #pragma unroll
            for (int fn = 0; fn < 2; ++fn)
                acc[fm][fn] = __builtin_amdgcn_mfma_f32_16x16x32_bf16(
                    a[fm], bb[fn], acc[fm][fn], 0, 0, 0);
        __syncthreads();
    }

    float* st = states + ((long long)(bz * NHEADS + h)) * HEADDIM * DSTATE;
    const int crow = (lane >> 4) * 4;
    const int ccol = lane & 15;
    #pragma unroll
    for (int fm = 0; fm < 4; ++fm)
        #pragma unroll
        for (int j = 0; j < 4; ++j) {
            int p = fm * 16 + crow + j;
            #pragma unroll
            for (int fn = 0; fn < 2; ++fn)
                st[p * DSTATE + wn + fn * 16 + ccol] = acc[fm][fn][j];
        }
}

// ============================================================
// Inter-chunk scan (in place: states[z] <- prev[z]).
// ============================================================
__global__ __launch_bounds__(256)
void chunk_scan(float* __restrict__ states, const float* __restrict__ cs)
{
    int f = blockIdx.x * 256 + threadIdx.x;
    int n = f & 127;
    int p = (f >> 7) & 63;
    int h = (f >> 13) & 31;
    int b = f >> 18;

    float carry = 0.f;
    for (int z = 0; z < NC; ++z) {
        long long idx = ((((long long)(b * NC + z) * NHEADS) + h) * HEADDIM + p) * DSTATE + n;
        float st = states[idx];
        states[idx] = carry;
        float cd = expf(cs[((long long)(b * NHEADS) + h) * SEQ + z * CHUNK + CHUNK - 1]);
        carry = carry * cd + st;
    }
}

// ============================================================
// Fused Y: per (b,z,h):
//   Y[l,p] = sum_{s<=l} S[l,s]*exp(cs_l-cs_s)*xd[s,p]          (phase 1)
//          + exp(cs_l) * sum_n C[l,n]*prev[p,n]                 (phase 2)
//          + D_h * x[l,p]                                       (epilogue)
// 4 waves, wave w owns rows [w*64, w*64+64), all 64 p-cols. MFMA 16x16x32.
// ============================================================
__global__ __launch_bounds__(256)
void y_fused(const bf16* __restrict__ Smat, const bf16* __restrict__ Cc,
             const bf16* __restrict__ xconv, const float* __restrict__ dtp,
             const float* __restrict__ cs, const float* __restrict__ prev,
             const float* __restrict__ Dv, unsigned short* __restrict__ y)
{
    const int h  = blockIdx.x & 31;
    const int bz = blockIdx.x >> 5;
    const int z  = bz & (NC - 1);
    const int b  = bz >> 4;
    const int tid = threadIdx.x;
    const int lane = tid & 63;
    const int wid = tid >> 6;
    const int frow = lane & 15;
    const int fk = lane >> 4;
    const int wr = wid * 64;

    __shared__ __attribute__((aligned(16))) short Ms[256][40];  // M tile / Ce tile
    __shared__ __attribute__((aligned(16))) short Xs[64][40];   // xdT tile / prev rows
    __shared__ float css[CHUNK];

    const long long csbase = ((long long)(b * NHEADS) + h) * SEQ + (long long)z * CHUNK;
    const long long rowbase = (long long)b * SEQ + (long long)z * CHUNK;

    css[tid] = cs[csbase + tid];
    __syncthreads();
    const float cl = css[tid];   // this thread stages row l=tid

    f32x4 acc[4][4];
    #pragma unroll
    for (int i = 0; i < 4; ++i)
        #pragma unroll
        for (int j = 0; j < 4; ++j) acc[i][j] = (f32x4)(0.0f);

    const unsigned short* Srow =
        (const unsigned short*)Smat + ((long long)bz * CHUNK + tid) * CHUNK;

    // ---- phase 1: M @ xdT  (K = s over 256) ----
    for (int s0 = 0; s0 < CHUNK; s0 += 32) {
        // stage M row l=tid, cols s0..s0+32
        {
            ushort4 v[8];
            #pragma unroll
            for (int g = 0; g < 8; ++g) v[g] = *(const ushort4*)(Srow + s0 + g * 4);
            const unsigned short* vv = (const unsigned short*)v;
            #pragma unroll
            for (int sc = 0; sc < 32; ++sc) {
                float m = (s0 + sc <= tid) ? bfu(vv[sc]) * expf(cl - css[s0 + sc]) : 0.f;
                Ms[tid][sc] = (short)f2bf(m);
            }
        }
        // stage xdT [64p][32s]
        {
            const int sl = tid >> 3;
            const int p8 = (tid & 7) * 8;
            long long r = rowbase + s0 + sl;
            const unsigned short* xp = (const unsigned short*)xconv + r * DSSM + h * 64 + p8;
            ushort4 a0 = *(const ushort4*)xp;
            ushort4 a1 = *(const ushort4*)(xp + 4);
            float sc_ = dtp[r * NHEADS + h];
            unsigned short t[8] = {a0.x,a0.y,a0.z,a0.w,a1.x,a1.y,a1.z,a1.w};
            #pragma unroll
            for (int j = 0; j < 8; ++j)
                Xs[p8 + j][sl] = (short)f2bf(bfu(t[j]) * sc_);
        }
        __syncthreads();
        bf16x8 a[4], bb[4];
        #pragma unroll
        for (int fm = 0; fm < 4; ++fm)
            a[fm] = *(const bf16x8*)&Ms[wr + fm * 16 + frow][fk * 8];
        #pragma unroll
        for (int fn = 0; fn < 4; ++fn)
            bb[fn] = *(const bf16x8*)&Xs[fn * 16 + frow][fk * 8];
        #pragma unroll
        for (int fm = 0; fm < 4; ++fm)
            #pragma unroll
            for (int fn = 0; fn < 4; ++fn)
                acc[fm][fn] = __builtin_amdgcn_mfma_f32_16x16x32_bf16(
                    a[fm], bb[fn], acc[fm][fn], 0, 0, 0);
        __syncthreads();
    }

    // ---- phase 2: Ce @ prev-rows  (K = n over 128) ----
    const float el = expf(cl);
    const unsigned short* Crow = (const unsigned short*)Cc + (rowbase + tid) * DSTATE;
    const float* pv = prev + (long long)(bz * NHEADS + h) * HEADDIM * DSTATE;
    for (int n0 = 0; n0 < DSTATE; n0 += 32) {
        // stage Ce row l=tid
        {
            ushort4 v[8];
            #pragma unroll
            for (int g = 0; g < 8; ++g) v[g] = *(const ushort4*)(Crow + n0 + g * 4);
            const unsigned short* vv = (const unsigned short*)v;
            #pragma unroll
            for (int nc2 = 0; nc2 < 32; ++nc2)
                Ms[tid][nc2] = (short)f2bf(bfu(vv[nc2]) * el);
        }
        // stage prev rows [64p][32n] (fp32 -> bf16, no transpose)
        {
            const int p = tid >> 2;
            const int n8 = (tid & 3) * 8;
            const float* pr = pv + p * DSTATE + n0 + n8;
            float4 f0 = *(const float4*)pr;
            float4 f1 = *(const float4*)(pr + 4);
            Xs[p][n8 + 0] = (short)f2bf(f0.x); Xs[p][n8 + 1] = (short)f2bf(f0.y);
            Xs[p][n8 + 2] = (short)f2bf(f0.z); Xs[p][n8 + 3] = (short)f2bf(f0.w);
            Xs[p][n8 + 4] = (short)f2bf(f1.x); Xs[p][n8 + 5] = (short)f2bf(f1.y);
            Xs[p][n8 + 6] = (short)f2bf(f1.z); Xs[p][n8 + 7] = (short)f2bf(f1.w);
        }
        __syncthreads();
        bf16x8 a[4], bb[4];
        #pragma unroll
        for (int fm = 0; fm < 4; ++fm)
            a[fm] = *(const bf16x8*)&Ms[wr + fm * 16 + frow][fk * 8];
        #pragma unroll
        for (int fn = 0; fn < 4; ++fn)
            bb[fn] = *(const bf16x8*)&Xs[fn * 16 + frow][fk * 8];
        #pragma unroll
        for (int fm = 0; fm < 4; ++fm)
            #pragma unroll
            for (int fn = 0; fn < 4; ++fn)
                acc[fm][fn] = __builtin_amdgcn_mfma_f32_16x16x32_bf16(
                    a[fm], bb[fn], acc[fm][fn], 0, 0, 0);
        __syncthreads();
    }

    // ---- epilogue: + D_h * x, write bf16 ----
    const float Dh = Dv[h];
    const int crow = (lane >> 4) * 4;
    const int ccol = lane & 15;
    #pragma unroll
    for (int fm = 0; fm < 4; ++fm) {
        #pragma unroll
        for (int j = 0; j < 4; ++j) {
            long long row = rowbase + wr + fm * 16 + crow + j;
            const unsigned short* xr = (const unsigned short*)xconv + row * DSSM + h * 64;
            unsigned short* yr = y + row * DSSM + h * 64;
            #pragma unroll
            for (int fn = 0; fn < 4; ++fn) {
                int p = fn * 16 + ccol;
                yr[p] = f2bf(acc[fm][fn][j] + Dh * bfu(xr[p]));
            }
        }
    }
}

// ============================================================
__global__ __launch_bounds__(256)
void gated_rmsnorm(bf16* __restrict__ y, const bf16* __restrict__ z,
                   const float* __restrict__ nw)
{
    const int row = blockIdx.x;
    const int tid = threadIdx.x;
    bf16* yr = y + (long long)row * DSSM;
    const bf16* zr = z + (long long)row * DSSM;

    float t[8];
    float ss = 0.f;
    const int c0 = tid * 8;
    #pragma unroll
    for (int j = 0; j < 8; ++j) {
        float zv = __bfloat162float(zr[c0 + j]);
        float tv = __bfloat162float(yr[c0 + j]) * siluf(zv);
        t[j] = tv;
        ss += tv * tv;
    }
    #pragma unroll
    for (int off = 32; off > 0; off >>= 1) ss += __shfl_down(ss, off);
    __shared__ float red[4];
    if ((tid & 63) == 0) red[tid >> 6] = ss;
    __syncthreads();
    float tot = red[0] + red[1] + red[2] + red[3];
    float rs = rsqrtf(tot / (float)DSSM + EPSF);
    #pragma unroll
    for (int j = 0; j < 8; ++j)
        yr[c0 + j] = __float2bfloat16(t[j] * rs * nw[c0 + j]);
}

// ============================================================
extern "C" void kernel_launch(void* const* d_in, const int* in_sizes, int n_in,
                              void* d_out, int out_size, void* d_ws, size_t ws_size,
                              hipStream_t stream)
{
    const float* inp     = (const float*)d_in[0];
    const float* W_in    = (const float*)d_in[1];
    const float* conv_w  = (const float*)d_in[2];
    const float* conv_b  = (const float*)d_in[3];
    const float* dt_bias = (const float*)d_in[4];
    const float* A_log   = (const float*)d_in[5];
    const float* Dv      = (const float*)d_in[6];
    const float* norm_w  = (const float*)d_in[7];
    const float* W_out   = (const float*)d_in[8];
    float* out = (float*)d_out;

    char* ws = (char*)d_ws;
    size_t off = 0;
    auto alloc = [&](size_t bytes) -> void* {
        void* p = (void*)(ws + off);
        off = (off + bytes + 255) & ~(size_t)255;
        return p;
    };
    const int MR = B_SZ * SEQ;   // 8192 token rows

    bf16*  zb     = (bf16*) alloc((size_t)MR * DSSM * 2);            // 33.55 MB
    bf16*  xbc    = (bf16*) alloc((size_t)MR * CONVDIM * 2);         // 37.75 MB (dead after conv)
    bf16*  xconv  = (bf16*) alloc((size_t)MR * DSSM * 2);            // 33.55 MB
    bf16*  Bc     = (bf16*) alloc((size_t)MR * DSTATE * 2);          // 2.10 MB
    bf16*  Cc     = (bf16*) alloc((size_t)MR * DSTATE * 2);          // 2.10 MB
    float* dtraw  = (float*)alloc((size_t)MR * NHEADS * 4);          // 1.05 MB
    float* dtp    = (float*)alloc((size_t)MR * NHEADS * 4);          // 1.05 MB
    float* cs     = (float*)alloc((size_t)B_SZ * NHEADS * SEQ * 4);  // 1.05 MB
    float* states = (float*)alloc((size_t)B_SZ * NC * NHEADS * HEADDIM * DSTATE * 4); // 33.55 MB
    unsigned short* Wob = (unsigned short*)alloc((size_t)DOUTSZ * DINNER * 2);        // 4.19 MB

    // aliases (lifetime-disjoint, stream-ordered):
    bf16*  Smat = (bf16*)xbc;                                        // after conv
    bf16*  ybuf = (bf16*)((char*)xbc + (size_t)B_SZ * NC * CHUNK * CHUNK * 2);
    unsigned short* inpb = (unsigned short*)states;                  // dead before states
    unsigned short* Wb   = (unsigned short*)xconv;                   // dead before conv writes xconv

    dim3 blk(256);

    // 0) casts to bf16
    cast_f32_bf16<<<dim3((MR * DMODEL) / (256 * 8)), blk, 0, stream>>>(inp, inpb);
    cast_f32_bf16<<<dim3((4384 * DMODEL) / (256 * 8)), blk, 0, stream>>>(W_in, Wb);
    cast_f32_bf16<<<dim3((DOUTSZ * DINNER) / (256 * 8)), blk, 0, stream>>>(W_out, Wob);

    // 1) in_proj: z (N=2048) and xBC (N=2304) via bf16 MFMA; dt (N=32) fp32
    gemm_mfma_nt<unsigned short><<<dim3(DSSM / 128, MR / 128), blk, 0, stream>>>(
        (const short*)inpb, (const short*)Wb, (unsigned short*)zb, MR, DSSM, DMODEL, 0, 0, 0);
    gemm_mfma_nt<unsigned short><<<dim3(CONVDIM / 128, MR / 128), blk, 0, stream>>>(
        (const short*)inpb, (const short*)(Wb + (size_t)DSSM * DMODEL),
        (unsigned short*)xbc, MR, CONVDIM, DMODEL, 0, 0, 0);
    gemm_nt<<<dim3(1, MR / BM, 1), blk, 0, stream>>>(
        inp, W_in + (size_t)(DSSM + CONVDIM) * DMODEL, dtraw,
        MR, NHEADS, DMODEL, DMODEL, DMODEL, NHEADS);

    // 2) conv + silu + split (xbc dead afterwards; overwrites Wb region via xconv)
    conv_silu<<<dim3(MR * 9), blk, 0, stream>>>(xbc, conv_w, conv_b, xconv, Bc, Cc);

    // 3) dtp = softplus(dt_raw + dt_bias)
    dtproj<<<dim3(MR * NHEADS / 256), blk, 0, stream>>>(dtraw, dt_bias, dtp);

    // 4) cumsum of dA per (b,h,chunk)
    cumsum_da<<<dim3(B_SZ * NHEADS * NC), blk, 0, stream>>>(dtp, A_log, cs);

    // 5) S = Cm @ Bm^T per (b,chunk) via bf16 MFMA -> Smat (aliases xbc)
    gemm_mfma_nt<unsigned short><<<dim3(CHUNK / 128, CHUNK / 128, B_SZ * NC), blk, 0, stream>>>(
        (const short*)Cc, (const short*)Bc, (unsigned short*)Smat, CHUNK, CHUNK, DSTATE,
        (long long)CHUNK * DSTATE, (long long)CHUNK * DSTATE, (long long)CHUNK * CHUNK);

    // 6) per-chunk states (MFMA)
    chunk_states_mfma<<<dim3(B_SZ * NC * NHEADS), blk, 0, stream>>>(Bc, xconv, dtp, cs, states);

    // 7) inter-chunk scan (in place -> prev)
    chunk_scan<<<dim3(B_SZ * NHEADS * HEADDIM * DSTATE / 256), blk, 0, stream>>>(states, cs);

    // 8) fused Y: Y_diag + Y_off + D*x -> ybuf
    y_fused<<<dim3(B_SZ * NC * NHEADS), blk, 0, stream>>>(
        Smat, Cc, xconv, dtp, cs, states, Dv, (unsigned short*)ybuf);

    // 9) gated RMSNorm (in place on ybuf)
    gated_rmsnorm<<<dim3(MR), blk, 0, stream>>>(ybuf, zb, norm_w);

    // 10) out GEMM: out = ybuf @ W_out^T  (bf16 MFMA, fp32 out)
    gemm_mfma_nt<float><<<dim3(DOUTSZ / 128, MR / 128), blk, 0, stream>>>(
        (const short*)ybuf, (const short*)Wob, out, MR, DOUTSZ, DINNER, 0, 0, 0);
}